// Round 2
// baseline (654.899 us; speedup 1.0000x reference)
//
#include <hip/hip_runtime.h>

// Problem: 16384 tokens x 128 experts router over hidden=2880, top-4 + softmax.
constexpr int T_TOK = 16384;
constexpr int NEXP  = 128;
constexpr int HID   = 2880;
constexpr int TOPK  = 4;

constexpr int BM = 128;   // token tile
constexpr int BK = 36;    // K tile: quad-stride 9 (odd) -> minimal LDS conflicts, unpadded
                          // (unpadded required by global_load_lds contiguity)

// ---------------------------------------------------------------------------
// Kernel 1: split-K partial GEMM, part[split][token][expert].
// Grid: 128 token-tiles * KSPLIT. 256 threads, 8x8 register tile per thread.
// Staging: global_load_lds width=16; each wave's 9 calls each fill one
// contiguous 1 KiB LDS run (lane L -> base + 16*L), per the wave-uniform-base
// hardware rule.
// ---------------------------------------------------------------------------
template <int KSPLIT>
__global__ __launch_bounds__(256, 4)
void gemm_partial(const float* __restrict__ x, const float* __restrict__ w,
                  float* __restrict__ part) {
    constexpr int KS  = HID / KSPLIT;
    constexpr int NIT = KS / BK;
    static_assert(KS % BK == 0, "");

    __shared__ float sm[2 * BM * BK];   // xs [128x36] then ws [128x36], 36.9 KB

    const int tid  = threadIdx.x;
    const int wv   = tid >> 6;
    const int lane = tid & 63;
    const int tx   = tid & 15;   // expert group
    const int ty   = tid >> 4;   // token group

    const int tile  = blockIdx.x / KSPLIT;
    const int split = blockIdx.x % KSPLIT;

    float acc[8][8];
#pragma unroll
    for (int i = 0; i < 8; ++i)
#pragma unroll
        for (int j = 0; j < 8; ++j) acc[i][j] = 0.f;

    const float* xb = x + (size_t)tile * BM * HID + (size_t)split * KS;
    const float* wb = w + (size_t)split * KS;

    for (int it = 0; it < NIT; ++it) {
        const int k0 = it * BK;
        // 2*128*36 floats = 2304 16B-chunks; 9 per thread. Chunk id chosen so
        // each wave covers 64 consecutive chunks (contiguous 1 KiB LDS).
#pragma unroll
        for (int r = 0; r < 9; ++r) {
            const int f  = ((r * 4 + wv) << 6) + lane;  // 0..2303
            const int fo = f << 2;                      // float offset in sm
            const float* g;
            if (fo < BM * BK) {
                g = xb + (size_t)(fo / BK) * HID + (k0 + fo % BK);
            } else {
                const int q = fo - BM * BK;
                g = wb + (size_t)(q / BK) * HID + (k0 + q % BK);
            }
            __builtin_amdgcn_global_load_lds(
                (const __attribute__((address_space(1))) void*)g,
                (__attribute__((address_space(3))) void*)&sm[fo], 16, 0, 0);
        }
        __syncthreads();

        const float* xs  = sm;
        const float* wsm = sm + BM * BK;
#pragma unroll
        for (int kk = 0; kk < BK; kk += 4) {
            float4 xq[8];
#pragma unroll
            for (int i = 0; i < 8; ++i)
                xq[i] = *reinterpret_cast<const float4*>(&xs[(ty + 16 * i) * BK + kk]);
#pragma unroll
            for (int j = 0; j < 8; ++j) {
                const float4 wq =
                    *reinterpret_cast<const float4*>(&wsm[(tx + 16 * j) * BK + kk]);
#pragma unroll
                for (int i = 0; i < 8; ++i) {
                    acc[i][j] = fmaf(xq[i].x, wq.x, acc[i][j]);
                    acc[i][j] = fmaf(xq[i].y, wq.y, acc[i][j]);
                    acc[i][j] = fmaf(xq[i].z, wq.z, acc[i][j]);
                    acc[i][j] = fmaf(xq[i].w, wq.w, acc[i][j]);
                }
            }
        }
        __syncthreads();
    }

#pragma unroll
    for (int i = 0; i < 8; ++i) {
        const int t = tile * BM + ty + 16 * i;
        float* p = part + ((size_t)split * T_TOK + t) * NEXP;
#pragma unroll
        for (int j = 0; j < 8; ++j) p[tx + 16 * j] = acc[i][j];
    }
}

// ---------------------------------------------------------------------------
// Kernel 2: reduce splits + bias (+vision bias), top-4 (jax tie-break: lower
// index wins), softmax over 4, dense scatter + indices (as float).
// One wave per token; lane l owns experts l and l+64.
// ---------------------------------------------------------------------------
template <int KSPLIT>
__global__ __launch_bounds__(256)
void topk_scatter(const float* __restrict__ part, const int* __restrict__ mm,
                  const float* __restrict__ bias, const float* __restrict__ vbias,
                  float* __restrict__ out) {
    const int lane = threadIdx.x & 63;
    const int wid  = threadIdx.x >> 6;
    const int t    = blockIdx.x * 4 + wid;

    const int e0 = lane, e1 = 64 + lane;
    float v0 = bias[e0];
    float v1 = bias[e1];
    if (mm[t] != 0) { v0 += vbias[e0]; v1 += vbias[e1]; }
#pragma unroll
    for (int s = 0; s < KSPLIT; ++s) {
        const float* p = part + ((size_t)s * T_TOK + t) * NEXP;
        v0 += p[e0];
        v1 += p[e1];
    }

    float lv0 = v0, lv1 = v1;
    float tv[TOPK];
    int   ti[TOPK];
#pragma unroll
    for (int k = 0; k < TOPK; ++k) {
        float bv; int bi;
        if (lv0 >= lv1) { bv = lv0; bi = e0; }   // tie -> lower index
        else            { bv = lv1; bi = e1; }
#pragma unroll
        for (int off = 32; off >= 1; off >>= 1) {
            float ov = __shfl_xor(bv, off, 64);
            int   oi = __shfl_xor(bi, off, 64);
            if (ov > bv || (ov == bv && oi < bi)) { bv = ov; bi = oi; }
        }
        tv[k] = bv;
        ti[k] = bi;
        if (bi == e0) lv0 = -__builtin_inff();
        if (bi == e1) lv1 = -__builtin_inff();
    }

    const float m = tv[0];
    float ex[TOPK], s = 0.f;
#pragma unroll
    for (int k = 0; k < TOPK; ++k) { ex[k] = expf(tv[k] - m); s += ex[k]; }
    const float inv = 1.0f / s;

    float s0 = 0.f, s1 = 0.f;
#pragma unroll
    for (int k = 0; k < TOPK; ++k) {
        const float p = ex[k] * inv;
        if (ti[k] == e0) s0 = p;
        if (ti[k] == e1) s1 = p;
    }
    out[(size_t)t * NEXP + e0] = s0;
    out[(size_t)t * NEXP + e1] = s1;
    if (lane < TOPK)
        out[(size_t)T_TOK * NEXP + (size_t)t * TOPK + lane] = (float)ti[lane];
}

extern "C" void kernel_launch(void* const* d_in, const int* in_sizes, int n_in,
                              void* d_out, int out_size, void* d_ws, size_t ws_size,
                              hipStream_t stream) {
    const float* x     = (const float*)d_in[0];   // (4,4096,2880) fp32
    const int*   mm    = (const int*)d_in[1];     // (4,4096) bool -> int32
    const float* w     = (const float*)d_in[2];   // (128,2880) fp32
    const float* bias  = (const float*)d_in[3];   // (128,)
    const float* vbias = (const float*)d_in[4];   // (128,)
    float* out  = (float*)d_out;                  // [scores 16384*128 | idx 16384*4]
    float* part = (float*)d_ws;

    const size_t need8 = (size_t)8 * T_TOK * NEXP * sizeof(float);  // 67.1 MB
    if (ws_size >= need8) {
        hipLaunchKernelGGL((gemm_partial<8>), dim3((T_TOK / BM) * 8), dim3(256), 0,
                           stream, x, w, part);
        hipLaunchKernelGGL((topk_scatter<8>), dim3(T_TOK / 4), dim3(256), 0, stream,
                           part, mm, bias, vbias, out);
    } else {
        hipLaunchKernelGGL((gemm_partial<4>), dim3((T_TOK / BM) * 4), dim3(256), 0,
                           stream, x, w, part);
        hipLaunchKernelGGL((topk_scatter<4>), dim3(T_TOK / 4), dim3(256), 0, stream,
                           part, mm, bias, vbias, out);
    }
}

// Round 3
// 414.693 us; speedup vs baseline: 1.5792x; 1.5792x over previous
//
#include <hip/hip_runtime.h>

// Problem: 16384 tokens x 128 experts router over hidden=2880, top-4 + softmax.
constexpr int T_TOK = 16384;
constexpr int NEXP  = 128;
constexpr int HID   = 2880;
constexpr int TOPK  = 4;

constexpr int BM = 128;   // token tile
constexpr int BK = 36;    // K tile (unpadded: required by global_load_lds contiguity)

// ---------------------------------------------------------------------------
// Kernel 1: split-K partial GEMM, part[split][token][expert].
// Grid: 128 token-tiles * KSPLIT. 256 threads, 8x8 register tile per thread.
// Staging: global_load_lds width=16 (wave-uniform base + lane*16 -> each wave
// fills one contiguous 1 KiB LDS run per call).
// NOTE: __launch_bounds__(256, 2) — round 2 proved that asking for 4 waves/EU
// makes the compiler allocate 64 VGPRs and spill the 64-reg accumulator to
// scratch (WRITE_SIZE 34->808 MB). With (256,2) this loop compiles to 128
// VGPRs (round-1 evidence), which still permits 4 waves/EU in hardware.
// ---------------------------------------------------------------------------
template <int KSPLIT>
__global__ __launch_bounds__(256, 2)
void gemm_partial(const float* __restrict__ x, const float* __restrict__ w,
                  float* __restrict__ part) {
    constexpr int KS  = HID / KSPLIT;
    constexpr int NIT = KS / BK;
    static_assert(KS % BK == 0, "");

    __shared__ float sm[2 * BM * BK];   // xs [128x36] then ws [128x36], 36.9 KB

    const int tid  = threadIdx.x;
    const int wv   = tid >> 6;
    const int lane = tid & 63;
    const int tx   = tid & 15;   // expert group
    const int ty   = tid >> 4;   // token group

    const int tile  = blockIdx.x / KSPLIT;
    const int split = blockIdx.x % KSPLIT;

    float acc[8][8];
#pragma unroll
    for (int i = 0; i < 8; ++i)
#pragma unroll
        for (int j = 0; j < 8; ++j) acc[i][j] = 0.f;

    const float* xb = x + (size_t)tile * BM * HID + (size_t)split * KS;
    const float* wb = w + (size_t)split * KS;

    for (int it = 0; it < NIT; ++it) {
        const int k0 = it * BK;
        // 2*128*36 floats = 2304 16B-chunks; 9 per thread. Chunk id chosen so
        // each wave covers 64 consecutive chunks (contiguous 1 KiB LDS).
#pragma unroll
        for (int r = 0; r < 9; ++r) {
            const int f  = ((r * 4 + wv) << 6) + lane;  // 0..2303
            const int fo = f << 2;                      // float offset in sm
            const float* g;
            if (fo < BM * BK) {
                g = xb + (size_t)(fo / BK) * HID + (k0 + fo % BK);
            } else {
                const int q = fo - BM * BK;
                g = wb + (size_t)(q / BK) * HID + (k0 + q % BK);
            }
            __builtin_amdgcn_global_load_lds(
                (const __attribute__((address_space(1))) void*)g,
                (__attribute__((address_space(3))) void*)&sm[fo], 16, 0, 0);
        }
        __syncthreads();

        const float* xs  = sm;
        const float* wsm = sm + BM * BK;
#pragma unroll
        for (int kk = 0; kk < BK; kk += 4) {
            float4 xq[8];
#pragma unroll
            for (int i = 0; i < 8; ++i)
                xq[i] = *reinterpret_cast<const float4*>(&xs[(ty + 16 * i) * BK + kk]);
#pragma unroll
            for (int j = 0; j < 8; ++j) {
                const float4 wq =
                    *reinterpret_cast<const float4*>(&wsm[(tx + 16 * j) * BK + kk]);
#pragma unroll
                for (int i = 0; i < 8; ++i) {
                    acc[i][j] = fmaf(xq[i].x, wq.x, acc[i][j]);
                    acc[i][j] = fmaf(xq[i].y, wq.y, acc[i][j]);
                    acc[i][j] = fmaf(xq[i].z, wq.z, acc[i][j]);
                    acc[i][j] = fmaf(xq[i].w, wq.w, acc[i][j]);
                }
            }
        }
        __syncthreads();
    }

#pragma unroll
    for (int i = 0; i < 8; ++i) {
        const int t = tile * BM + ty + 16 * i;
        float* p = part + ((size_t)split * T_TOK + t) * NEXP;
#pragma unroll
        for (int j = 0; j < 8; ++j) p[tx + 16 * j] = acc[i][j];
    }
}

// ---------------------------------------------------------------------------
// Kernel 2: reduce splits + bias (+vision bias), top-4 (jax tie-break: lower
// index wins), softmax over 4, dense scatter + indices (as float).
// One wave per token; lane l owns experts l and l+64.
// ---------------------------------------------------------------------------
template <int KSPLIT>
__global__ __launch_bounds__(256)
void topk_scatter(const float* __restrict__ part, const int* __restrict__ mm,
                  const float* __restrict__ bias, const float* __restrict__ vbias,
                  float* __restrict__ out) {
    const int lane = threadIdx.x & 63;
    const int wid  = threadIdx.x >> 6;
    const int t    = blockIdx.x * 4 + wid;

    const int e0 = lane, e1 = 64 + lane;
    float v0 = bias[e0];
    float v1 = bias[e1];
    if (mm[t] != 0) { v0 += vbias[e0]; v1 += vbias[e1]; }
#pragma unroll
    for (int s = 0; s < KSPLIT; ++s) {
        const float* p = part + ((size_t)s * T_TOK + t) * NEXP;
        v0 += p[e0];
        v1 += p[e1];
    }

    float lv0 = v0, lv1 = v1;
    float tv[TOPK];
    int   ti[TOPK];
#pragma unroll
    for (int k = 0; k < TOPK; ++k) {
        float bv; int bi;
        if (lv0 >= lv1) { bv = lv0; bi = e0; }   // tie -> lower index
        else            { bv = lv1; bi = e1; }
#pragma unroll
        for (int off = 32; off >= 1; off >>= 1) {
            float ov = __shfl_xor(bv, off, 64);
            int   oi = __shfl_xor(bi, off, 64);
            if (ov > bv || (ov == bv && oi < bi)) { bv = ov; bi = oi; }
        }
        tv[k] = bv;
        ti[k] = bi;
        if (bi == e0) lv0 = -__builtin_inff();
        if (bi == e1) lv1 = -__builtin_inff();
    }

    const float m = tv[0];
    float ex[TOPK], s = 0.f;
#pragma unroll
    for (int k = 0; k < TOPK; ++k) { ex[k] = expf(tv[k] - m); s += ex[k]; }
    const float inv = 1.0f / s;

    float s0 = 0.f, s1 = 0.f;
#pragma unroll
    for (int k = 0; k < TOPK; ++k) {
        const float p = ex[k] * inv;
        if (ti[k] == e0) s0 = p;
        if (ti[k] == e1) s1 = p;
    }
    out[(size_t)t * NEXP + e0] = s0;
    out[(size_t)t * NEXP + e1] = s1;
    if (lane < TOPK)
        out[(size_t)T_TOK * NEXP + (size_t)t * TOPK + lane] = (float)ti[lane];
}

extern "C" void kernel_launch(void* const* d_in, const int* in_sizes, int n_in,
                              void* d_out, int out_size, void* d_ws, size_t ws_size,
                              hipStream_t stream) {
    const float* x     = (const float*)d_in[0];   // (4,4096,2880) fp32
    const int*   mm    = (const int*)d_in[1];     // (4,4096) bool -> int32
    const float* w     = (const float*)d_in[2];   // (128,2880) fp32
    const float* bias  = (const float*)d_in[3];   // (128,)
    const float* vbias = (const float*)d_in[4];   // (128,)
    float* out  = (float*)d_out;                  // [scores 16384*128 | idx 16384*4]
    float* part = (float*)d_ws;

    const size_t need8 = (size_t)8 * T_TOK * NEXP * sizeof(float);  // 67.1 MB
    if (ws_size >= need8) {
        hipLaunchKernelGGL((gemm_partial<8>), dim3((T_TOK / BM) * 8), dim3(256), 0,
                           stream, x, w, part);
        hipLaunchKernelGGL((topk_scatter<8>), dim3(T_TOK / 4), dim3(256), 0, stream,
                           part, mm, bias, vbias, out);
    } else {
        hipLaunchKernelGGL((gemm_partial<4>), dim3((T_TOK / BM) * 4), dim3(256), 0,
                           stream, x, w, part);
        hipLaunchKernelGGL((topk_scatter<4>), dim3(T_TOK / 4), dim3(256), 0, stream,
                           part, mm, bias, vbias, out);
    }
}

// Round 4
// 311.249 us; speedup vs baseline: 2.1041x; 1.3324x over previous
//
#include <hip/hip_runtime.h>

// 16384 tokens x 128 experts router over hidden=2880, top-4 + softmax.
// GEMM via bf16 MFMA with 3-way split-precision (x,w = h+m+l bf16; products
// hh,hm,mh,mm,hl,lh) -> per-term relative error ~2^-22, fp32-class logits, so
// top-k indices match the fp32 reference (gap statistics need err << 1e-4).
constexpr int T_TOK = 16384;
constexpr int NEXP  = 128;
constexpr int HID   = 2880;
constexpr int TOPK  = 4;

constexpr int KSPLIT = 6;            // 768 blocks = 3 blocks/CU
constexpr int KS     = HID / KSPLIT; // 480
constexpr int BM     = 128;
constexpr int BK     = 32;
constexpr int NIT    = KS / BK;      // 15
constexpr int WELEMS = NEXP * HID;   // 368640

typedef __attribute__((ext_vector_type(8))) short bf16x8;
typedef __attribute__((ext_vector_type(4))) float f32x4;

// x = h + m + l; h = RNE bf16, m = trunc bf16 of residual, l = trunc of rest.
// |h-err path| <= ~2^-22 relative after recombination.
__device__ inline void split3(float f, unsigned& hb, unsigned& mb, unsigned& lb) {
    unsigned u = __float_as_uint(f);
    unsigned rne = u + 0x7FFFu + ((u >> 16) & 1u);
    hb = rne & 0xFFFF0000u;
    float r = f - __uint_as_float(hb);
    mb = __float_as_uint(r) & 0xFFFF0000u;
    lb = __float_as_uint(r - __uint_as_float(mb));
}

// ---------------------------------------------------------------------------
// Kernel 0: split w (128x2880 fp32) into three bf16 planes in ws.
// ---------------------------------------------------------------------------
__global__ __launch_bounds__(256)
void w_split_kernel(const float* __restrict__ w, unsigned short* __restrict__ wh,
                    unsigned short* __restrict__ wm, unsigned short* __restrict__ wl) {
    int i = blockIdx.x * 256 + threadIdx.x;
    if (i < WELEMS) {
        unsigned hb, mb, lb;
        split3(w[i], hb, mb, lb);
        wh[i] = (unsigned short)(hb >> 16);
        wm[i] = (unsigned short)(mb >> 16);
        wl[i] = (unsigned short)(lb >> 16);
    }
}

// ---------------------------------------------------------------------------
// Kernel 1: MFMA split-K GEMM. part[split][token][expert].
// 4 waves; wave wv owns rows wv*32..wv*32+31 (2 row-frags) x all 128 experts
// (8 col-frags). x loaded global->registers (each element touched by exactly
// one wave), split in-reg; w_h/m/l tiles staged to LDS via global_load_lds.
// A-frag layout: A[m=lane&15][k=(lane>>4)*8+j]; C/D: col=lane&15,
// row=(lane>>4)*4+reg (HW-verified mappings).
// ---------------------------------------------------------------------------
__global__ __launch_bounds__(256, 2)
void gemm_mfma(const float* __restrict__ x,
               const unsigned short* __restrict__ wh,
               const unsigned short* __restrict__ wm,
               const unsigned short* __restrict__ wl,
               float* __restrict__ part) {
    __shared__ unsigned short bs[3 * NEXP * BK];   // h | m | l tiles, 24.6 KB

    const int tid  = threadIdx.x;
    const int wv   = tid >> 6;
    const int lane = tid & 63;
    const int lm   = lane & 15;
    const int lq   = lane >> 4;

    const int tile   = blockIdx.x / KSPLIT;
    const int split  = blockIdx.x % KSPLIT;
    const int k_base = split * KS;

    f32x4 acc[2][8];
#pragma unroll
    for (int i = 0; i < 2; ++i)
#pragma unroll
        for (int j = 0; j < 8; ++j) acc[i][j] = (f32x4){0.f, 0.f, 0.f, 0.f};

    const float* xb = x + (size_t)tile * BM * HID + k_base;

    for (int it = 0; it < NIT; ++it) {
        const int k0 = k_base + it * BK;
        // --- stage B tiles (3 x 128x32 bf16 = 24 KB): 1536 16B-chunks, 6/thread.
        // chunk c = r*256 + wv*64 + lane -> LDS dest = base + lane*16 (wave-
        // uniform rule). r<2 -> h plane, r<4 -> m, else l (compile-time).
#pragma unroll
        for (int r = 0; r < 6; ++r) {
            const int c  = r * 256 + wv * 64 + lane;   // 0..1535
            const int cc = c & 511;
            const int e  = cc >> 2;
            const int kq = (cc & 3) << 3;
            const unsigned short* plane = (r < 2) ? wh : (r < 4) ? wm : wl;
            const unsigned short* src = plane + (size_t)e * HID + k0 + kq;
            __builtin_amdgcn_global_load_lds(
                (const __attribute__((address_space(1))) void*)src,
                (__attribute__((address_space(3))) void*)&bs[c * 8], 16, 0, 0);
        }

        // --- load + split x fragments (overlaps the LDS-DMA wait)
        unsigned ah[2][4], am[2][4], al[2][4];
#pragma unroll
        for (int i = 0; i < 2; ++i) {
            const float* ap =
                xb + (size_t)(wv * 32 + i * 16 + lm) * HID + it * BK + lq * 8;
            float4 a0 = *reinterpret_cast<const float4*>(ap);
            float4 a1 = *reinterpret_cast<const float4*>(ap + 4);
            float fv[8] = {a0.x, a0.y, a0.z, a0.w, a1.x, a1.y, a1.z, a1.w};
            unsigned hb[8], mb[8], lb[8];
#pragma unroll
            for (int e2 = 0; e2 < 8; ++e2) split3(fv[e2], hb[e2], mb[e2], lb[e2]);
#pragma unroll
            for (int p = 0; p < 4; ++p) {
                ah[i][p] = __builtin_amdgcn_perm(hb[2*p+1], hb[2*p], 0x07060302u);
                am[i][p] = __builtin_amdgcn_perm(mb[2*p+1], mb[2*p], 0x07060302u);
                al[i][p] = __builtin_amdgcn_perm(lb[2*p+1], lb[2*p], 0x07060302u);
            }
        }
        __syncthreads();

#pragma unroll
        for (int j = 0; j < 8; ++j) {
            const int boff = (j * 16 + lm) * BK + lq * 8;
            bf16x8 Bh = *reinterpret_cast<const bf16x8*>(&bs[boff]);
            bf16x8 Bm = *reinterpret_cast<const bf16x8*>(&bs[NEXP * BK + boff]);
            bf16x8 Bl = *reinterpret_cast<const bf16x8*>(&bs[2 * NEXP * BK + boff]);
#pragma unroll
            for (int i = 0; i < 2; ++i) {
                union { unsigned u[4]; bf16x8 v; } Ah, Am, Al;
#pragma unroll
                for (int p = 0; p < 4; ++p) {
                    Ah.u[p] = ah[i][p]; Am.u[p] = am[i][p]; Al.u[p] = al[i][p];
                }
                acc[i][j] = __builtin_amdgcn_mfma_f32_16x16x32_bf16(Ah.v, Bh, acc[i][j], 0, 0, 0);
                acc[i][j] = __builtin_amdgcn_mfma_f32_16x16x32_bf16(Ah.v, Bm, acc[i][j], 0, 0, 0);
                acc[i][j] = __builtin_amdgcn_mfma_f32_16x16x32_bf16(Am.v, Bh, acc[i][j], 0, 0, 0);
                acc[i][j] = __builtin_amdgcn_mfma_f32_16x16x32_bf16(Am.v, Bm, acc[i][j], 0, 0, 0);
                acc[i][j] = __builtin_amdgcn_mfma_f32_16x16x32_bf16(Ah.v, Bl, acc[i][j], 0, 0, 0);
                acc[i][j] = __builtin_amdgcn_mfma_f32_16x16x32_bf16(Al.v, Bh, acc[i][j], 0, 0, 0);
            }
        }
        __syncthreads();
    }

    // --- write partials: row = quad*4 + reg, col = lane&15 (C/D layout)
#pragma unroll
    for (int i = 0; i < 2; ++i) {
        const int trow = tile * BM + wv * 32 + i * 16 + lq * 4;
#pragma unroll
        for (int j = 0; j < 8; ++j) {
            const int e = j * 16 + lm;
            float* p = part + ((size_t)split * T_TOK + trow) * NEXP + e;
#pragma unroll
            for (int r = 0; r < 4; ++r) p[(size_t)r * NEXP] = acc[i][j][r];
        }
    }
}

// ---------------------------------------------------------------------------
// Kernel 2: reduce splits + bias (+vision bias), top-4 (tie -> lower index),
// softmax over 4, dense scatter + indices (as float). One wave per token.
// ---------------------------------------------------------------------------
__global__ __launch_bounds__(256)
void topk_scatter(const float* __restrict__ part, const int* __restrict__ mm,
                  const float* __restrict__ bias, const float* __restrict__ vbias,
                  float* __restrict__ out) {
    const int lane = threadIdx.x & 63;
    const int wid  = threadIdx.x >> 6;
    const int t    = blockIdx.x * 4 + wid;

    const int e0 = lane, e1 = 64 + lane;
    float v0 = bias[e0];
    float v1 = bias[e1];
    if (mm[t] != 0) { v0 += vbias[e0]; v1 += vbias[e1]; }
#pragma unroll
    for (int s = 0; s < KSPLIT; ++s) {
        const float* p = part + ((size_t)s * T_TOK + t) * NEXP;
        v0 += p[e0];
        v1 += p[e1];
    }

    float lv0 = v0, lv1 = v1;
    float tv[TOPK];
    int   ti[TOPK];
#pragma unroll
    for (int k = 0; k < TOPK; ++k) {
        float bv; int bi;
        if (lv0 >= lv1) { bv = lv0; bi = e0; }
        else            { bv = lv1; bi = e1; }
#pragma unroll
        for (int off = 32; off >= 1; off >>= 1) {
            float ov = __shfl_xor(bv, off, 64);
            int   oi = __shfl_xor(bi, off, 64);
            if (ov > bv || (ov == bv && oi < bi)) { bv = ov; bi = oi; }
        }
        tv[k] = bv;
        ti[k] = bi;
        if (bi == e0) lv0 = -__builtin_inff();
        if (bi == e1) lv1 = -__builtin_inff();
    }

    const float m = tv[0];
    float ex[TOPK], s = 0.f;
#pragma unroll
    for (int k = 0; k < TOPK; ++k) { ex[k] = expf(tv[k] - m); s += ex[k]; }
    const float inv = 1.0f / s;

    float s0 = 0.f, s1 = 0.f;
#pragma unroll
    for (int k = 0; k < TOPK; ++k) {
        const float p = ex[k] * inv;
        if (ti[k] == e0) s0 = p;
        if (ti[k] == e1) s1 = p;
    }
    out[(size_t)t * NEXP + e0] = s0;
    out[(size_t)t * NEXP + e1] = s1;
    if (lane < TOPK)
        out[(size_t)T_TOK * NEXP + (size_t)t * TOPK + lane] = (float)ti[lane];
}

extern "C" void kernel_launch(void* const* d_in, const int* in_sizes, int n_in,
                              void* d_out, int out_size, void* d_ws, size_t ws_size,
                              hipStream_t stream) {
    const float* x     = (const float*)d_in[0];   // (4,4096,2880) fp32
    const int*   mm    = (const int*)d_in[1];     // (4,4096) bool -> int32
    const float* w     = (const float*)d_in[2];   // (128,2880) fp32
    const float* bias  = (const float*)d_in[3];   // (128,)
    const float* vbias = (const float*)d_in[4];   // (128,)
    float* out  = (float*)d_out;                  // [scores 16384*128 | idx 16384*4]

    // ws layout: partials (6*16384*128 fp32 = 50.3 MB) | wh | wm | wl bf16 planes
    float* part = (float*)d_ws;
    const size_t part_bytes = (size_t)KSPLIT * T_TOK * NEXP * sizeof(float);
    unsigned short* whp = (unsigned short*)((char*)d_ws + part_bytes);
    unsigned short* wmp = whp + WELEMS;
    unsigned short* wlp = wmp + WELEMS;

    hipLaunchKernelGGL(w_split_kernel, dim3((WELEMS + 255) / 256), dim3(256), 0,
                       stream, w, whp, wmp, wlp);
    hipLaunchKernelGGL(gemm_mfma, dim3((T_TOK / BM) * KSPLIT), dim3(256), 0, stream,
                       x, whp, wmp, wlp, part);
    hipLaunchKernelGGL(topk_scatter, dim3(T_TOK / 4), dim3(256), 0, stream,
                       part, mm, bias, vbias, out);
}

// Round 5
// 310.108 us; speedup vs baseline: 2.1118x; 1.0037x over previous
//
#include <hip/hip_runtime.h>

// 16384 tokens x 128 experts router over hidden=2880, top-4 + softmax.
// GEMM via bf16 MFMA, 3-way split precision (x,w = h+m+l bf16; products
// hh,hm,mh,mm,hl,lh -> ~2^-22 relative error, fp32-class logits, exact top-k).
constexpr int T_TOK = 16384;
constexpr int NEXP  = 128;
constexpr int HID   = 2880;
constexpr int TOPK  = 4;

constexpr int KSPLIT = 8;             // grid 1024 = even rounds at 2 or 4 blocks/CU
constexpr int KCH    = HID / 32;      // 90 k-chunks of 32; split unevenly 11/12
constexpr int BM     = 128;
constexpr int BK     = 32;
constexpr int WELEMS = NEXP * HID;

typedef __attribute__((ext_vector_type(8))) short bf16x8;
typedef __attribute__((ext_vector_type(4))) float f32x4;

__device__ inline void split3(float f, unsigned& hb, unsigned& mb, unsigned& lb) {
    unsigned u = __float_as_uint(f);
    unsigned rne = u + 0x7FFFu + ((u >> 16) & 1u);
    hb = rne & 0xFFFF0000u;
    float r = f - __uint_as_float(hb);
    mb = __float_as_uint(r) & 0xFFFF0000u;
    lb = __float_as_uint(r - __uint_as_float(mb));
}

// ---------------------------------------------------------------------------
// Kernel 0: split w into three bf16 planes in ws.
// ---------------------------------------------------------------------------
__global__ __launch_bounds__(256)
void w_split_kernel(const float* __restrict__ w, unsigned short* __restrict__ wh,
                    unsigned short* __restrict__ wm, unsigned short* __restrict__ wl) {
    int i = blockIdx.x * 256 + threadIdx.x;
    if (i < WELEMS) {
        unsigned hb, mb, lb;
        split3(w[i], hb, mb, lb);
        wh[i] = (unsigned short)(hb >> 16);
        wm[i] = (unsigned short)(mb >> 16);
        wl[i] = (unsigned short)(lb >> 16);
    }
}

// ---------------------------------------------------------------------------
// Kernel 1: MFMA split-K GEMM with double-buffered B-staging.
// Pipeline per iter: barrier (drains DMA issued ~96 MFMAs ago) -> issue DMA
// for it+1 into other buffer -> split current x regs -> prefetch x for it+1
// -> 96 MFMAs on current buffer. One barrier per iter; DMA and x loads are
// in flight across the whole MFMA block.
// ---------------------------------------------------------------------------
__global__ __launch_bounds__(256, 2)
void gemm_mfma(const float* __restrict__ x,
               const unsigned short* __restrict__ wh,
               const unsigned short* __restrict__ wm,
               const unsigned short* __restrict__ wl,
               float* __restrict__ part) {
    __shared__ unsigned short bs[2][3 * NEXP * BK];   // 2 x 24.6 KB

    const int tid  = threadIdx.x;
    const int wv   = tid >> 6;
    const int lane = tid & 63;
    const int lm   = lane & 15;
    const int lq   = lane >> 4;

    const int tile  = blockIdx.x / KSPLIT;
    const int split = blockIdx.x % KSPLIT;
    const int kcb   = (KCH * split) / KSPLIT;        // first k-chunk
    const int nit   = (KCH * (split + 1)) / KSPLIT - kcb;  // 11 or 12

    f32x4 acc[2][8];
#pragma unroll
    for (int i = 0; i < 2; ++i)
#pragma unroll
        for (int j = 0; j < 8; ++j) acc[i][j] = (f32x4){0.f, 0.f, 0.f, 0.f};

    const float* xb = x + (size_t)tile * BM * HID;

    auto stage = [&](int it, int buf) {
        const int k0 = (kcb + it) * 32;
        // 3 planes x 128 experts x 32 = 1536 16B-chunks, 6/thread; each wave's
        // 64 chunks are contiguous in LDS (wave-uniform base + lane*16).
#pragma unroll
        for (int r = 0; r < 6; ++r) {
            const int c  = (r * 4 + wv) * 64 + lane;   // 0..1535
            const int cc = c & 511;
            const int e  = cc >> 2;
            const int kq = (cc & 3) << 3;
            const unsigned short* plane = (r < 2) ? wh : (r < 4) ? wm : wl;
            const unsigned short* src = plane + (size_t)e * HID + k0 + kq;
            __builtin_amdgcn_global_load_lds(
                (const __attribute__((address_space(1))) void*)src,
                (__attribute__((address_space(3))) void*)&bs[buf][c * 8], 16, 0, 0);
        }
    };
    auto loadx = [&](int it, float4 xr[2][2]) {
        const int k0 = (kcb + it) * 32;
#pragma unroll
        for (int i = 0; i < 2; ++i) {
            const float* ap = xb + (size_t)(wv * 32 + i * 16 + lm) * HID + k0 + lq * 8;
            xr[i][0] = *reinterpret_cast<const float4*>(ap);
            xr[i][1] = *reinterpret_cast<const float4*>(ap + 4);
        }
    };

    float4 xr[2][2];
    stage(0, 0);
    loadx(0, xr);

    for (int it = 0; it < nit; ++it) {
        const int cur = it & 1;
        __syncthreads();                    // drains DMA/loads for this iter
        if (it + 1 < nit) stage(it + 1, cur ^ 1);

        // split current x into packed bf16 h/m/l A-fragments
        unsigned ah[2][4], am[2][4], al[2][4];
#pragma unroll
        for (int i = 0; i < 2; ++i) {
            float fv[8] = {xr[i][0].x, xr[i][0].y, xr[i][0].z, xr[i][0].w,
                           xr[i][1].x, xr[i][1].y, xr[i][1].z, xr[i][1].w};
            unsigned hb[8], mb[8], lb[8];
#pragma unroll
            for (int e2 = 0; e2 < 8; ++e2) split3(fv[e2], hb[e2], mb[e2], lb[e2]);
#pragma unroll
            for (int p = 0; p < 4; ++p) {
                ah[i][p] = __builtin_amdgcn_perm(hb[2*p+1], hb[2*p], 0x07060302u);
                am[i][p] = __builtin_amdgcn_perm(mb[2*p+1], mb[2*p], 0x07060302u);
                al[i][p] = __builtin_amdgcn_perm(lb[2*p+1], lb[2*p], 0x07060302u);
            }
        }
        if (it + 1 < nit) loadx(it + 1, xr);   // in flight across MFMA block

#pragma unroll
        for (int j = 0; j < 8; ++j) {
            const int boff = (j * 16 + lm) * BK + lq * 8;
            bf16x8 Bh = *reinterpret_cast<const bf16x8*>(&bs[cur][boff]);
            bf16x8 Bm = *reinterpret_cast<const bf16x8*>(&bs[cur][NEXP * BK + boff]);
            bf16x8 Bl = *reinterpret_cast<const bf16x8*>(&bs[cur][2 * NEXP * BK + boff]);
#pragma unroll
            for (int i = 0; i < 2; ++i) {
                union { unsigned u[4]; bf16x8 v; } Ah, Am, Al;
#pragma unroll
                for (int p = 0; p < 4; ++p) {
                    Ah.u[p] = ah[i][p]; Am.u[p] = am[i][p]; Al.u[p] = al[i][p];
                }
                acc[i][j] = __builtin_amdgcn_mfma_f32_16x16x32_bf16(Ah.v, Bh, acc[i][j], 0, 0, 0);
                acc[i][j] = __builtin_amdgcn_mfma_f32_16x16x32_bf16(Ah.v, Bm, acc[i][j], 0, 0, 0);
                acc[i][j] = __builtin_amdgcn_mfma_f32_16x16x32_bf16(Am.v, Bh, acc[i][j], 0, 0, 0);
                acc[i][j] = __builtin_amdgcn_mfma_f32_16x16x32_bf16(Am.v, Bm, acc[i][j], 0, 0, 0);
                acc[i][j] = __builtin_amdgcn_mfma_f32_16x16x32_bf16(Ah.v, Bl, acc[i][j], 0, 0, 0);
                acc[i][j] = __builtin_amdgcn_mfma_f32_16x16x32_bf16(Al.v, Bh, acc[i][j], 0, 0, 0);
            }
        }
    }

    // C/D layout: col = lane&15, row = quad*4 + reg
#pragma unroll
    for (int i = 0; i < 2; ++i) {
        const int trow = tile * BM + wv * 32 + i * 16 + lq * 4;
#pragma unroll
        for (int j = 0; j < 8; ++j) {
            const int e = j * 16 + lm;
            float* p = part + ((size_t)split * T_TOK + trow) * NEXP + e;
#pragma unroll
            for (int r = 0; r < 4; ++r) p[(size_t)r * NEXP] = acc[i][j][r];
        }
    }
}

// ---------------------------------------------------------------------------
// Kernel 2: reduce splits + bias (+vision bias), top-4 (tie -> lower index),
// softmax over 4, dense scatter + indices (as float). One wave per token.
// ---------------------------------------------------------------------------
__global__ __launch_bounds__(256)
void topk_scatter(const float* __restrict__ part, const int* __restrict__ mm,
                  const float* __restrict__ bias, const float* __restrict__ vbias,
                  float* __restrict__ out) {
    const int lane = threadIdx.x & 63;
    const int wid  = threadIdx.x >> 6;
    const int t    = blockIdx.x * 4 + wid;

    const int e0 = lane, e1 = 64 + lane;
    float v0 = bias[e0];
    float v1 = bias[e1];
    if (mm[t] != 0) { v0 += vbias[e0]; v1 += vbias[e1]; }
#pragma unroll
    for (int s = 0; s < KSPLIT; ++s) {
        const float* p = part + ((size_t)s * T_TOK + t) * NEXP;
        v0 += p[e0];
        v1 += p[e1];
    }

    float lv0 = v0, lv1 = v1;
    float tv[TOPK];
    int   ti[TOPK];
#pragma unroll
    for (int k = 0; k < TOPK; ++k) {
        float bv; int bi;
        if (lv0 >= lv1) { bv = lv0; bi = e0; }
        else            { bv = lv1; bi = e1; }
#pragma unroll
        for (int off = 32; off >= 1; off >>= 1) {
            float ov = __shfl_xor(bv, off, 64);
            int   oi = __shfl_xor(bi, off, 64);
            if (ov > bv || (ov == bv && oi < bi)) { bv = ov; bi = oi; }
        }
        tv[k] = bv;
        ti[k] = bi;
        if (bi == e0) lv0 = -__builtin_inff();
        if (bi == e1) lv1 = -__builtin_inff();
    }

    const float m = tv[0];
    float ex[TOPK], s = 0.f;
#pragma unroll
    for (int k = 0; k < TOPK; ++k) { ex[k] = expf(tv[k] - m); s += ex[k]; }
    const float inv = 1.0f / s;

    float s0 = 0.f, s1 = 0.f;
#pragma unroll
    for (int k = 0; k < TOPK; ++k) {
        const float p = ex[k] * inv;
        if (ti[k] == e0) s0 = p;
        if (ti[k] == e1) s1 = p;
    }
    out[(size_t)t * NEXP + e0] = s0;
    out[(size_t)t * NEXP + e1] = s1;
    if (lane < TOPK)
        out[(size_t)T_TOK * NEXP + (size_t)t * TOPK + lane] = (float)ti[lane];
}

extern "C" void kernel_launch(void* const* d_in, const int* in_sizes, int n_in,
                              void* d_out, int out_size, void* d_ws, size_t ws_size,
                              hipStream_t stream) {
    const float* x     = (const float*)d_in[0];   // (4,4096,2880) fp32
    const int*   mm    = (const int*)d_in[1];     // (4,4096) bool -> int32
    const float* w     = (const float*)d_in[2];   // (128,2880) fp32
    const float* bias  = (const float*)d_in[3];   // (128,)
    const float* vbias = (const float*)d_in[4];   // (128,)
    float* out  = (float*)d_out;                  // [scores 16384*128 | idx 16384*4]

    // ws: partials (8*16384*128 fp32 = 67.1 MB) | wh | wm | wl bf16 planes
    float* part = (float*)d_ws;
    const size_t part_bytes = (size_t)KSPLIT * T_TOK * NEXP * sizeof(float);
    unsigned short* whp = (unsigned short*)((char*)d_ws + part_bytes);
    unsigned short* wmp = whp + WELEMS;
    unsigned short* wlp = wmp + WELEMS;

    hipLaunchKernelGGL(w_split_kernel, dim3((WELEMS + 255) / 256), dim3(256), 0,
                       stream, w, whp, wmp, wlp);
    hipLaunchKernelGGL(gemm_mfma, dim3((T_TOK / BM) * KSPLIT), dim3(256), 0, stream,
                       x, whp, wmp, wlp, part);
    hipLaunchKernelGGL(topk_scatter, dim3(T_TOK / 4), dim3(256), 0, stream,
                       part, mm, bias, vbias, out);
}